// Round 9
// baseline (140.073 us; speedup 1.0000x reference)
//
#include <hip/hip_runtime.h>
#include <math.h>

namespace {

constexpr int B = 2048;
constexpr int C = 20000;
constexpr int D = 512;
constexpr int LMAX = 8;

constexpr int BMt = 128, BNt = 128, BKt = 64;
constexpr int NROWT = B / BMt;               // 16 row tiles
constexpr int NPAN  = (C + BNt - 1) / BNt;   // 157 col panels (last has 32 valid)
constexpr int KST   = D / BKt;               // 8 K-steps
constexpr int CHUNKS = 1024;                 // f16x8 (16B) slots per (tile,kstep)
constexpr int NWG   = NROWT * NPAN;          // 2512 (divisible by 8 XCDs)

constexpr float S_SCALE = 30.0f;
constexpr float COS_M = 0.87758256189037271f;   // cos(0.5)
constexpr float SIN_M = 0.47942553860420301f;   // sin(0.5)
constexpr float TH    = -0.87758256189037271f;  // cos(pi - 0.5)
constexpr float MM    = 0.23971276930210156f;   // sin(pi - 0.5) * 0.5
constexpr float MFIX  = 30.0f;                  // fixed softmax shift: |logits| <= 30

typedef float f32x16 __attribute__((ext_vector_type(16)));
typedef _Float16 f16x8 __attribute__((ext_vector_type(8)));

__device__ __forceinline__ void mfma_16(f32x16& acc, f16x8 a, f16x8 b) {
    acc = __builtin_amdgcn_mfma_f32_32x32x16_f16(a, b, acc, 0, 0, 0);
}

__device__ __forceinline__ float wave_sum(float v) {
    #pragma unroll
    for (int off = 1; off < 64; off <<= 1) v += __shfl_xor(v, off, 64);
    return v;
}

// Fused norm + pack for f, pre-normalized so GEMM emits cosine directly.
// grid = NROWT blocks; norms computed ONCE per tile, then all 8 k-steps packed
// (reads are L2-hot after the norm pass).
// Layout: Ap[rowtile][kstep][chunk q = m_frag*4 + k16][lane] (f16x8).
// Slot (q,l): row = (q>>2)*32 + (l&31), k = (q&3)*16 + (l>>5)*8 .. +8.
__global__ void pack_a_kernel(const float* __restrict__ f, f16x8* __restrict__ Ap,
                              float* __restrict__ fn) {
    __shared__ float sInv[BMt];
    const int bx = blockIdx.x;
    const int t = threadIdx.x, lane = t & 63, w = t >> 6;

    for (int rr = 0; rr < 32; ++rr) {                 // wave w owns rows w*32..+31
        const int lrow = w * 32 + rr;
        const int row = bx * BMt + lrow;
        const float4* p = reinterpret_cast<const float4*>(f + (size_t)row * D + lane * 8);
        const float4 a = p[0], b = p[1];
        float s2 = a.x*a.x + a.y*a.y + a.z*a.z + a.w*a.w
                 + b.x*b.x + b.y*b.y + b.z*b.z + b.w*b.w;
        s2 = wave_sum(s2);
        if (lane == 0) {
            const float nrm = sqrtf(s2);
            sInv[lrow] = 1.0f / fmaxf(nrm, 1e-8f);
            fn[row] = nrm;
        }
    }
    __syncthreads();

    for (int s = 0; s < KST; ++s) {
        f16x8* blk = Ap + (size_t)(bx * KST + s) * CHUNKS;
        #pragma unroll
        for (int i = 0; i < 4; ++i) {
            const int v = i * 256 + t;
            const int q = v >> 6, l = v & 63;
            const int lrow = (q >> 2) * 32 + (l & 31);
            const int row = bx * BMt + lrow;
            const int k = s * BKt + (q & 3) * 16 + (l >> 5) * 8;
            const float4 x0 = *reinterpret_cast<const float4*>(&f[(size_t)row * D + k]);
            const float4 x1 = *reinterpret_cast<const float4*>(&f[(size_t)row * D + k + 4]);
            const float xs[8] = {x0.x, x0.y, x0.z, x0.w, x1.x, x1.y, x1.z, x1.w};
            const float sc = sInv[lrow];
            f16x8 hv;
            #pragma unroll
            for (int j = 0; j < 8; ++j) hv[j] = (_Float16)(xs[j] * sc);
            blk[v] = hv;
        }
    }
}

// Fused norm + pack for W columns; zero-fill cols >= C.
// grid = NPAN blocks; norms once, then all 8 k-steps packed (L2-hot re-read).
__global__ void pack_b_kernel(const float* __restrict__ wsrc, f16x8* __restrict__ Bp,
                              float* __restrict__ wn) {
    __shared__ float sInv[BNt];
    const int pan = blockIdx.x;
    const int t = threadIdx.x, lane = t & 63, w = t >> 6;

    for (int rr = 0; rr < 32; ++rr) {
        const int lcol = w * 32 + rr;
        const int col = pan * BNt + lcol;
        float s2 = 0.0f;
        if (col < C) {
            const float4* p = reinterpret_cast<const float4*>(wsrc + (size_t)col * D + lane * 8);
            const float4 a = p[0], b = p[1];
            s2 = a.x*a.x + a.y*a.y + a.z*a.z + a.w*a.w
               + b.x*b.x + b.y*b.y + b.z*b.z + b.w*b.w;
        }
        s2 = wave_sum(s2);
        if (lane == 0) {
            const float nrm = sqrtf(s2);
            sInv[lcol] = (col < C) ? (1.0f / fmaxf(nrm, 1e-8f)) : 0.0f;
            if (col < C) wn[col] = nrm;
        }
    }
    __syncthreads();

    for (int s = 0; s < KST; ++s) {
        f16x8* blk = Bp + (size_t)(pan * KST + s) * CHUNKS;
        #pragma unroll
        for (int i = 0; i < 4; ++i) {
            const int v = i * 256 + t;
            const int q = v >> 6, l = v & 63;
            const int lcol = (q >> 2) * 32 + (l & 31);
            const int col = pan * BNt + lcol;
            const int k = s * BKt + (q & 3) * 16 + (l >> 5) * 8;
            f16x8 hv = (f16x8)0;
            if (col < C) {
                const float4 x0 = *reinterpret_cast<const float4*>(&wsrc[(size_t)col * D + k]);
                const float4 x1 = *reinterpret_cast<const float4*>(&wsrc[(size_t)col * D + k + 4]);
                const float xs[8] = {x0.x, x0.y, x0.z, x0.w, x1.x, x1.y, x1.z, x1.w};
                const float sc = sInv[lcol];
                #pragma unroll
                for (int j = 0; j < 8; ++j) hv[j] = (_Float16)(xs[j] * sc);
            }
            blk[v] = hv;
        }
    }
}

// MFMA GEMM on normalized f16 panels, fragments global->VGPR (no LDS staging).
// TRANSPOSED accumulate: mfma(b, a) puts output ROWS on lane&31, so the
// Z-partial reduction is per-lane in-register + one shfl_xor(32).
// pZ[row][panel] = sum_cols exp(30*cos - 30).
// 1-D grid 2512 with XCD-aware swizzle; 4 waves = 2x2 of 64x64 per wave.
__global__ __launch_bounds__(256) void
gemm_mfma_kernel(const f16x8* __restrict__ Ap, const f16x8* __restrict__ Bp,
                 float* __restrict__ pZ)
{
    __shared__ float sRed[BMt][2];
    const int wgid = blockIdx.x;
    const int swz = (wgid & 7) * (NWG / 8) + (wgid >> 3);   // bijective (NWG%8==0)
    const int bx = swz & 15;          // row tile
    const int by = swz >> 4;          // panel
    const int tid  = threadIdx.x;
    const int lane = tid & 63;
    const int half = lane >> 5, l31 = lane & 31;
    const int w    = tid >> 6;
    const int wm   = w >> 1;          // 0..1
    const int wnn  = w & 1;           // 0..1

    const f16x8* Aw = Ap + (size_t)bx * KST * CHUNKS + wm * 512 + lane;
    const f16x8* Bw = Bp + (size_t)by * KST * CHUNKS + wnn * 512 + lane;

    f32x16 accT00, accT01, accT10, accT11;   // [n_frag][m_frag], rows on lanes
    #pragma unroll
    for (int i = 0; i < 16; ++i) { accT00[i] = 0.f; accT01[i] = 0.f; accT10[i] = 0.f; accT11[i] = 0.f; }

    #pragma unroll 4
    for (int s = 0; s < KST; ++s) {
        const f16x8* As = Aw + s * CHUNKS;
        const f16x8* Bs = Bw + s * CHUNKS;
        #pragma unroll
        for (int k16 = 0; k16 < 4; ++k16) {
            const f16x8 a0 = As[k16 * 64];
            const f16x8 a1 = As[256 + k16 * 64];
            const f16x8 b0 = Bs[k16 * 64];
            const f16x8 b1 = Bs[256 + k16 * 64];
            mfma_16(accT00, b0, a0);  // rows wm*64+l31,    cols wnn*64 + r-map
            mfma_16(accT01, b0, a1);  // rows wm*64+32+l31, cols wnn*64 + r-map
            mfma_16(accT10, b1, a0);  // rows wm*64+l31,    cols +32
            mfma_16(accT11, b1, a1);  // rows wm*64+32+l31, cols +32
        }
    }

    // ---- epilogue: per-lane row partials, single cross-lane step ----
    float zA = 0.0f;   // row = wm*64 + l31
    float zB = 0.0f;   // row = wm*64 + 32 + l31
    const int cbase = by * BNt + wnn * 64 + 4 * half;
    #pragma unroll
    for (int r = 0; r < 16; ++r) {
        const int cb = cbase + (r & 3) + 8 * (r >> 2);
        const float eA0 = (cb      < C) ? __expf(fmaf(accT00[r], S_SCALE, -MFIX)) : 0.0f;
        const float eB0 = (cb      < C) ? __expf(fmaf(accT01[r], S_SCALE, -MFIX)) : 0.0f;
        const float eA1 = (cb + 32 < C) ? __expf(fmaf(accT10[r], S_SCALE, -MFIX)) : 0.0f;
        const float eB1 = (cb + 32 < C) ? __expf(fmaf(accT11[r], S_SCALE, -MFIX)) : 0.0f;
        zA += eA0 + eA1;
        zB += eB0 + eB1;
    }
    zA += __shfl_xor(zA, 32, 64);    // combine the two col-halves of each row
    zB += __shfl_xor(zB, 32, 64);
    if (half == 0) {
        sRed[wm * 64 + l31][wnn]      = zA;
        sRed[wm * 64 + 32 + l31][wnn] = zB;
    }
    __syncthreads();
    if (tid < BMt) {
        pZ[(size_t)(bx * BMt + tid) * NPAN + by] = sRed[tid][0] + sRed[tid][1];
    }
}

// One wave per row: sum NPAN partials (fixed shift M=30), exact fp32 target
// logits + ArcFace margin, correct Z, emit per-row loss.
__global__ void finalize_kernel(const float* __restrict__ f, const float* __restrict__ w,
                                const float* __restrict__ fn, const float* __restrict__ wn,
                                const int* __restrict__ pinds, const int* __restrict__ lengths,
                                const float* __restrict__ pZ, float* __restrict__ loss)
{
    const int b = blockIdx.x;
    const int lane = threadIdx.x;

    float Zp = 0.0f;
    for (int p = lane; p < NPAN; p += 64) Zp += pZ[(size_t)b * NPAN + p];
    Zp = wave_sum(Zp);

    const float4* fp = reinterpret_cast<const float4*>(f + (size_t)b * D);
    const float4 a0 = fp[lane * 2 + 0];
    const float4 a1 = fp[lane * 2 + 1];
    const float fnb = fn[b];
    const int len = lengths[b];

    float opl[LMAX], ops[LMAX];
    int cs[LMAX];
    #pragma unroll
    for (int j = 0; j < LMAX; ++j) {
        const int c = pinds[(size_t)b * LMAX + j];
        cs[j] = c;
        const float4* wp = reinterpret_cast<const float4*>(w + (size_t)c * D);
        const float4 w0 = wp[lane * 2 + 0];
        const float4 w1 = wp[lane * 2 + 1];
        float d = a0.x*w0.x + a0.y*w0.y + a0.z*w0.z + a0.w*w0.w
                + a1.x*w1.x + a1.y*w1.y + a1.z*w1.z + a1.w*w1.w;
        d = wave_sum(d);
        const float cosv = d / fmaxf(fnb * wn[c], 1e-8f);
        const float sine = sqrtf(fminf(fmaxf(1.0f - cosv * cosv, 0.0f), 1.0f));
        float phi = cosv * COS_M - sine * SIN_M;
        phi = (cosv > TH) ? phi : (cosv - MM);
        opl[j] = S_SCALE * cosv;
        ops[j] = S_SCALE * phi;
    }

    // correct Z for unique positive classes (margin applied), then ragged CE
    float Zc = Zp;
    for (int j = 0; j < len; ++j) {
        bool dup = false;
        for (int jj = 0; jj < j; ++jj) dup = dup || (cs[jj] == cs[j]);
        if (!dup) Zc += expf(ops[j] - MFIX) - expf(opl[j] - MFIX);
    }
    const float lZ = logf(Zc);
    float acc = 0.0f;
    for (int j = 0; j < len; ++j) acc += (MFIX + lZ - ops[j]);
    const float Lf = (float)len;
    if (lane == 0) loss[b] = acc / (Lf * Lf);
}

__global__ void reduce_kernel(const float* __restrict__ loss, float* __restrict__ out) {
    __shared__ float sdata[256];
    const int t = threadIdx.x;
    float s = 0.0f;
    for (int i = t; i < B; i += 256) s += loss[i];
    sdata[t] = s;
    __syncthreads();
    for (int off = 128; off > 0; off >>= 1) {
        if (t < off) sdata[t] += sdata[t + off];
        __syncthreads();
    }
    if (t == 0) out[0] = sdata[0] * (1.0f / (float)B);
}

} // anonymous namespace

extern "C" void kernel_launch(void* const* d_in, const int* in_sizes, int n_in,
                              void* d_out, int out_size, void* d_ws, size_t ws_size,
                              hipStream_t stream) {
    const float* f   = (const float*)d_in[0];
    // d_in[1] = labels [B,C] — not needed (reconstructed from pinds/lengths)
    const float* w   = (const float*)d_in[2];
    const int* pinds = (const int*)d_in[3];
    const int* lens  = (const int*)d_in[4];
    float* out = (float*)d_out;

    char* ws = (char*)d_ws;
    size_t off = 0;
    auto alloc = [&](size_t bytes) { void* p = ws + off; off = (off + bytes + 255) & ~(size_t)255; return p; };

    float* wn   = (float*)alloc(C * 4);
    float* fn   = (float*)alloc(B * 4);
    float* pZ   = (float*)alloc((size_t)B * NPAN * 4);
    float* loss = (float*)alloc(B * 4);
    f16x8* Ap   = (f16x8*)alloc((size_t)NROWT * KST * CHUNKS * 16);
    f16x8* Bp   = (f16x8*)alloc((size_t)NPAN  * KST * CHUNKS * 16);

    pack_a_kernel<<<dim3(NROWT), 256, 0, stream>>>(f, Ap, fn);
    pack_b_kernel<<<dim3(NPAN), 256, 0, stream>>>(w, Bp, wn);
    gemm_mfma_kernel<<<dim3(NWG), 256, 0, stream>>>(Ap, Bp, pZ);
    finalize_kernel<<<dim3(B), 64, 0, stream>>>(f, w, fn, wn, pinds, lens, pZ, loss);
    reduce_kernel<<<dim3(1), 256, 0, stream>>>(loss, out);
}

// Round 10
// 126.490 us; speedup vs baseline: 1.1074x; 1.1074x over previous
//
#include <hip/hip_runtime.h>
#include <math.h>

namespace {

constexpr int B = 2048;
constexpr int C = 20000;
constexpr int D = 512;
constexpr int LMAX = 8;

constexpr int BMt = 128, BNt = 128, BKt = 64;
constexpr int NROWT = B / BMt;               // 16 row tiles
constexpr int NPAN  = (C + BNt - 1) / BNt;   // 157 col panels (last has 32 valid)
constexpr int KST   = D / BKt;               // 8 K-steps
constexpr int CHUNKS = 1024;                 // f16x8 (16B) slots per (tile,kstep)
constexpr int NWG   = NROWT * NPAN;          // 2512 (divisible by 8 XCDs)

constexpr float S_SCALE = 30.0f;
constexpr float COS_M = 0.87758256189037271f;   // cos(0.5)
constexpr float SIN_M = 0.47942553860420301f;   // sin(0.5)
constexpr float TH    = -0.87758256189037271f;  // cos(pi - 0.5)
constexpr float MM    = 0.23971276930210156f;   // sin(pi - 0.5) * 0.5
constexpr float MFIX  = 30.0f;                  // fixed softmax shift: |logits| <= 30

typedef float f32x16 __attribute__((ext_vector_type(16)));
typedef _Float16 f16x8 __attribute__((ext_vector_type(8)));

__device__ __forceinline__ void mfma_16(f32x16& acc, f16x8 a, f16x8 b) {
    acc = __builtin_amdgcn_mfma_f32_32x32x16_f16(a, b, acc, 0, 0, 0);
}

__device__ __forceinline__ float wave_sum(float v) {
    #pragma unroll
    for (int off = 1; off < 64; off <<= 1) v += __shfl_xor(v, off, 64);
    return v;
}

// Fused norm + pack for f (wide grid: norms recomputed per k-step block —
// redundant reads are L2/L3-hot and parallelism wins; R9 taught us that).
// grid (NROWT, KST). Layout: Ap[rowtile][kstep][chunk q = m_frag*4 + k16][lane].
// Slot (q,l): row = (q>>2)*32 + (l&31), k = (q&3)*16 + (l>>5)*8 .. +8.
__global__ void pack_a_kernel(const float* __restrict__ f, f16x8* __restrict__ Ap,
                              float* __restrict__ fn) {
    __shared__ float sInv[BMt];
    const int bx = blockIdx.x, s = blockIdx.y;
    const int t = threadIdx.x, lane = t & 63, w = t >> 6;

    for (int rr = 0; rr < 32; ++rr) {                 // wave w owns rows w*32..+31
        const int lrow = w * 32 + rr;
        const int row = bx * BMt + lrow;
        const float4* p = reinterpret_cast<const float4*>(f + (size_t)row * D + lane * 8);
        const float4 a = p[0], b = p[1];
        float s2 = a.x*a.x + a.y*a.y + a.z*a.z + a.w*a.w
                 + b.x*b.x + b.y*b.y + b.z*b.z + b.w*b.w;
        s2 = wave_sum(s2);
        if (lane == 0) {
            const float nrm = sqrtf(s2);
            sInv[lrow] = 1.0f / fmaxf(nrm, 1e-8f);
            if (s == 0) fn[row] = nrm;
        }
    }
    __syncthreads();

    f16x8* blk = Ap + (size_t)(bx * KST + s) * CHUNKS;
    #pragma unroll
    for (int i = 0; i < 4; ++i) {
        const int v = i * 256 + t;
        const int q = v >> 6, l = v & 63;
        const int lrow = (q >> 2) * 32 + (l & 31);
        const int row = bx * BMt + lrow;
        const int k = s * BKt + (q & 3) * 16 + (l >> 5) * 8;
        const float4 x0 = *reinterpret_cast<const float4*>(&f[(size_t)row * D + k]);
        const float4 x1 = *reinterpret_cast<const float4*>(&f[(size_t)row * D + k + 4]);
        const float xs[8] = {x0.x, x0.y, x0.z, x0.w, x1.x, x1.y, x1.z, x1.w};
        const float sc = sInv[lrow];
        f16x8 hv;
        #pragma unroll
        for (int j = 0; j < 8; ++j) hv[j] = (_Float16)(xs[j] * sc);
        blk[v] = hv;
    }
}

// Fused norm + pack for W columns (wide grid, 2 k-steps per block); zero-fill
// cols >= C.
__global__ void pack_b_kernel(const float* __restrict__ wsrc, f16x8* __restrict__ Bp,
                              float* __restrict__ wn) {
    __shared__ float sInv[BNt];
    const int pan = blockIdx.x, sg = blockIdx.y;
    const int t = threadIdx.x, lane = t & 63, w = t >> 6;

    for (int rr = 0; rr < 32; ++rr) {
        const int lcol = w * 32 + rr;
        const int col = pan * BNt + lcol;
        float s2 = 0.0f;
        if (col < C) {
            const float4* p = reinterpret_cast<const float4*>(wsrc + (size_t)col * D + lane * 8);
            const float4 a = p[0], b = p[1];
            s2 = a.x*a.x + a.y*a.y + a.z*a.z + a.w*a.w
               + b.x*b.x + b.y*b.y + b.z*b.z + b.w*b.w;
        }
        s2 = wave_sum(s2);
        if (lane == 0) {
            const float nrm = sqrtf(s2);
            sInv[lcol] = (col < C) ? (1.0f / fmaxf(nrm, 1e-8f)) : 0.0f;
            if (sg == 0 && col < C) wn[col] = nrm;
        }
    }
    __syncthreads();

    for (int ss = 0; ss < 2; ++ss) {
        const int s = sg * 2 + ss;
        f16x8* blk = Bp + (size_t)(pan * KST + s) * CHUNKS;
        #pragma unroll
        for (int i = 0; i < 4; ++i) {
            const int v = i * 256 + t;
            const int q = v >> 6, l = v & 63;
            const int lcol = (q >> 2) * 32 + (l & 31);
            const int col = pan * BNt + lcol;
            const int k = s * BKt + (q & 3) * 16 + (l >> 5) * 8;
            f16x8 hv = (f16x8)0;
            if (col < C) {
                const float4 x0 = *reinterpret_cast<const float4*>(&wsrc[(size_t)col * D + k]);
                const float4 x1 = *reinterpret_cast<const float4*>(&wsrc[(size_t)col * D + k + 4]);
                const float xs[8] = {x0.x, x0.y, x0.z, x0.w, x1.x, x1.y, x1.z, x1.w};
                const float sc = sInv[lcol];
                #pragma unroll
                for (int j = 0; j < 8; ++j) hv[j] = (_Float16)(xs[j] * sc);
            }
            blk[v] = hv;
        }
    }
}

// MFMA GEMM on normalized f16 panels, fragments global->VGPR (no LDS staging,
// no main-loop barriers). TRANSPOSED accumulate: mfma(b, a) puts output ROWS
// on lane&31 -> Z-partial is per-lane in-register + one shfl_xor(32).
// __launch_bounds__(256,4): cap VGPR at 128 -> 4 blocks/CU (occupancy probe).
__global__ __launch_bounds__(256, 4) void
gemm_mfma_kernel(const f16x8* __restrict__ Ap, const f16x8* __restrict__ Bp,
                 float* __restrict__ pZ)
{
    __shared__ float sRed[BMt][2];
    const int wgid = blockIdx.x;
    const int swz = (wgid & 7) * (NWG / 8) + (wgid >> 3);   // bijective (NWG%8==0)
    const int bx = swz & 15;          // row tile
    const int by = swz >> 4;          // panel
    const int tid  = threadIdx.x;
    const int lane = tid & 63;
    const int half = lane >> 5, l31 = lane & 31;
    const int w    = tid >> 6;
    const int wm   = w >> 1;          // 0..1
    const int wnn  = w & 1;           // 0..1

    const f16x8* Aw = Ap + (size_t)bx * KST * CHUNKS + wm * 512 + lane;
    const f16x8* Bw = Bp + (size_t)by * KST * CHUNKS + wnn * 512 + lane;

    f32x16 accT00, accT01, accT10, accT11;   // [n_frag][m_frag], rows on lanes
    #pragma unroll
    for (int i = 0; i < 16; ++i) { accT00[i] = 0.f; accT01[i] = 0.f; accT10[i] = 0.f; accT11[i] = 0.f; }

    #pragma unroll 2
    for (int s = 0; s < KST; ++s) {
        const f16x8* As = Aw + s * CHUNKS;
        const f16x8* Bs = Bw + s * CHUNKS;
        #pragma unroll
        for (int k16 = 0; k16 < 4; ++k16) {
            const f16x8 a0 = As[k16 * 64];
            const f16x8 a1 = As[256 + k16 * 64];
            const f16x8 b0 = Bs[k16 * 64];
            const f16x8 b1 = Bs[256 + k16 * 64];
            mfma_16(accT00, b0, a0);  // rows wm*64+l31,    cols wnn*64 + r-map
            mfma_16(accT01, b0, a1);  // rows wm*64+32+l31, cols wnn*64 + r-map
            mfma_16(accT10, b1, a0);  // rows wm*64+l31,    cols +32
            mfma_16(accT11, b1, a1);  // rows wm*64+32+l31, cols +32
        }
    }

    // ---- epilogue: per-lane row partials, single cross-lane step ----
    float zA = 0.0f;   // row = wm*64 + l31
    float zB = 0.0f;   // row = wm*64 + 32 + l31
    const int cbase = by * BNt + wnn * 64 + 4 * half;
    #pragma unroll
    for (int r = 0; r < 16; ++r) {
        const int cb = cbase + (r & 3) + 8 * (r >> 2);
        const float eA0 = (cb      < C) ? __expf(fmaf(accT00[r], S_SCALE, -MFIX)) : 0.0f;
        const float eB0 = (cb      < C) ? __expf(fmaf(accT01[r], S_SCALE, -MFIX)) : 0.0f;
        const float eA1 = (cb + 32 < C) ? __expf(fmaf(accT10[r], S_SCALE, -MFIX)) : 0.0f;
        const float eB1 = (cb + 32 < C) ? __expf(fmaf(accT11[r], S_SCALE, -MFIX)) : 0.0f;
        zA += eA0 + eA1;
        zB += eB0 + eB1;
    }
    zA += __shfl_xor(zA, 32, 64);    // combine the two col-halves of each row
    zB += __shfl_xor(zB, 32, 64);
    if (half == 0) {
        sRed[wm * 64 + l31][wnn]      = zA;
        sRed[wm * 64 + 32 + l31][wnn] = zB;
    }
    __syncthreads();
    if (tid < BMt) {
        pZ[(size_t)(bx * BMt + tid) * NPAN + by] = sRed[tid][0] + sRed[tid][1];
    }
}

// One wave per row: sum NPAN partials (fixed shift M=30), exact fp32 target
// logits + ArcFace margin, correct Z, emit per-row loss.
__global__ void finalize_kernel(const float* __restrict__ f, const float* __restrict__ w,
                                const float* __restrict__ fn, const float* __restrict__ wn,
                                const int* __restrict__ pinds, const int* __restrict__ lengths,
                                const float* __restrict__ pZ, float* __restrict__ loss)
{
    const int b = blockIdx.x;
    const int lane = threadIdx.x;

    float Zp = 0.0f;
    for (int p = lane; p < NPAN; p += 64) Zp += pZ[(size_t)b * NPAN + p];
    Zp = wave_sum(Zp);

    const float4* fp = reinterpret_cast<const float4*>(f + (size_t)b * D);
    const float4 a0 = fp[lane * 2 + 0];
    const float4 a1 = fp[lane * 2 + 1];
    const float fnb = fn[b];
    const int len = lengths[b];

    float opl[LMAX], ops[LMAX];
    int cs[LMAX];
    #pragma unroll
    for (int j = 0; j < LMAX; ++j) {
        const int c = pinds[(size_t)b * LMAX + j];
        cs[j] = c;
        const float4* wp = reinterpret_cast<const float4*>(w + (size_t)c * D);
        const float4 w0 = wp[lane * 2 + 0];
        const float4 w1 = wp[lane * 2 + 1];
        float d = a0.x*w0.x + a0.y*w0.y + a0.z*w0.z + a0.w*w0.w
                + a1.x*w1.x + a1.y*w1.y + a1.z*w1.z + a1.w*w1.w;
        d = wave_sum(d);
        const float cosv = d / fmaxf(fnb * wn[c], 1e-8f);
        const float sine = sqrtf(fminf(fmaxf(1.0f - cosv * cosv, 0.0f), 1.0f));
        float phi = cosv * COS_M - sine * SIN_M;
        phi = (cosv > TH) ? phi : (cosv - MM);
        opl[j] = S_SCALE * cosv;
        ops[j] = S_SCALE * phi;
    }

    // correct Z for unique positive classes (margin applied), then ragged CE
    float Zc = Zp;
    for (int j = 0; j < len; ++j) {
        bool dup = false;
        for (int jj = 0; jj < j; ++jj) dup = dup || (cs[jj] == cs[j]);
        if (!dup) Zc += expf(ops[j] - MFIX) - expf(opl[j] - MFIX);
    }
    const float lZ = logf(Zc);
    float acc = 0.0f;
    for (int j = 0; j < len; ++j) acc += (MFIX + lZ - ops[j]);
    const float Lf = (float)len;
    if (lane == 0) loss[b] = acc / (Lf * Lf);
}

__global__ void reduce_kernel(const float* __restrict__ loss, float* __restrict__ out) {
    __shared__ float sdata[256];
    const int t = threadIdx.x;
    float s = 0.0f;
    for (int i = t; i < B; i += 256) s += loss[i];
    sdata[t] = s;
    __syncthreads();
    for (int off = 128; off > 0; off >>= 1) {
        if (t < off) sdata[t] += sdata[t + off];
        __syncthreads();
    }
    if (t == 0) out[0] = sdata[0] * (1.0f / (float)B);
}

} // anonymous namespace

extern "C" void kernel_launch(void* const* d_in, const int* in_sizes, int n_in,
                              void* d_out, int out_size, void* d_ws, size_t ws_size,
                              hipStream_t stream) {
    const float* f   = (const float*)d_in[0];
    // d_in[1] = labels [B,C] — not needed (reconstructed from pinds/lengths)
    const float* w   = (const float*)d_in[2];
    const int* pinds = (const int*)d_in[3];
    const int* lens  = (const int*)d_in[4];
    float* out = (float*)d_out;

    char* ws = (char*)d_ws;
    size_t off = 0;
    auto alloc = [&](size_t bytes) { void* p = ws + off; off = (off + bytes + 255) & ~(size_t)255; return p; };

    float* wn   = (float*)alloc(C * 4);
    float* fn   = (float*)alloc(B * 4);
    float* pZ   = (float*)alloc((size_t)B * NPAN * 4);
    float* loss = (float*)alloc(B * 4);
    f16x8* Ap   = (f16x8*)alloc((size_t)NROWT * KST * CHUNKS * 16);
    f16x8* Bp   = (f16x8*)alloc((size_t)NPAN  * KST * CHUNKS * 16);

    pack_a_kernel<<<dim3(NROWT, KST), 256, 0, stream>>>(f, Ap, fn);
    pack_b_kernel<<<dim3(NPAN, KST / 2), 256, 0, stream>>>(w, Bp, wn);
    gemm_mfma_kernel<<<dim3(NWG), 256, 0, stream>>>(Ap, Bp, pZ);
    finalize_kernel<<<dim3(B), 64, 0, stream>>>(f, w, fn, wn, pinds, lens, pZ, loss);
    reduce_kernel<<<dim3(1), 256, 0, stream>>>(loss, out);
}

// Round 11
// 108.880 us; speedup vs baseline: 1.2865x; 1.1617x over previous
//
#include <hip/hip_runtime.h>
#include <math.h>

namespace {

constexpr int B = 2048;
constexpr int C = 20000;
constexpr int D = 512;
constexpr int LMAX = 8;

constexpr int BMt = 128, BNt = 128, BKt = 64;
constexpr int NROWT = B / BMt;               // 16 row tiles
constexpr int NPAN  = (C + BNt - 1) / BNt;   // 157 col panels (last has 32 valid)
constexpr int KST   = D / BKt;               // 8 K-steps
constexpr int SLOTS = 512;                   // 16B slots per (tile,kstep): q2=m_frag*2+k32
constexpr int NWG   = NROWT * NPAN;          // 2512 (divisible by 8 XCDs)

constexpr float S_SCALE = 30.0f;
constexpr float COS_M = 0.87758256189037271f;   // cos(0.5)
constexpr float SIN_M = 0.47942553860420301f;   // sin(0.5)
constexpr float TH    = -0.87758256189037271f;  // cos(pi - 0.5)
constexpr float MM    = 0.23971276930210156f;   // sin(pi - 0.5) * 0.5
constexpr float MFIX  = 30.0f;                  // fixed softmax shift: |logits| <= 30

typedef float f32x16 __attribute__((ext_vector_type(16)));

__device__ __forceinline__ void mfma_fp8_t(f32x16& acc, long bfrag, long afrag) {
    // transposed: builtin(A=bfrag, B=afrag) -> D cols (lane&31) = logit ROWS
    acc = __builtin_amdgcn_mfma_f32_32x32x16_fp8_fp8(bfrag, afrag, acc, 0, 0, 0);
}

// 8 fp32 -> 8 fp8 e4m3 bytes (hardware RNE pack), element j = byte j
__device__ __forceinline__ unsigned long long pack8_fp8(const float* xs, float sc) {
    int d0 = __builtin_amdgcn_cvt_pk_fp8_f32(xs[0] * sc, xs[1] * sc, 0, false);
    d0 = __builtin_amdgcn_cvt_pk_fp8_f32(xs[2] * sc, xs[3] * sc, d0, true);
    int d1 = __builtin_amdgcn_cvt_pk_fp8_f32(xs[4] * sc, xs[5] * sc, 0, false);
    d1 = __builtin_amdgcn_cvt_pk_fp8_f32(xs[6] * sc, xs[7] * sc, d1, true);
    return (unsigned long long)(unsigned)d0 | ((unsigned long long)(unsigned)d1 << 32);
}

__device__ __forceinline__ float wave_sum(float v) {
    #pragma unroll
    for (int off = 1; off < 64; off <<= 1) v += __shfl_xor(v, off, 64);
    return v;
}

// Fused norm + pack for f -> fp8 e4m3, pre-normalized (GEMM emits cosine).
// grid (NROWT, KST); wide grid, norms recomputed per k-step (L2/L3-hot).
// Slot u = q2*64 + l, q2 = m_frag*2 + k32. Slot.x/.y = k16 pair:
//   half h elements j: row = m_frag*32 + (l&31), k = k32*32 + h*16 + (l>>5)*8 + j.
__global__ void pack_a_kernel(const float* __restrict__ f, ulonglong2* __restrict__ Ap,
                              float* __restrict__ fn) {
    __shared__ float sInv[BMt];
    const int bx = blockIdx.x, s = blockIdx.y;
    const int t = threadIdx.x, lane = t & 63, w = t >> 6;

    for (int rr = 0; rr < 32; ++rr) {                 // wave w owns rows w*32..+31
        const int lrow = w * 32 + rr;
        const int row = bx * BMt + lrow;
        const float4* p = reinterpret_cast<const float4*>(f + (size_t)row * D + lane * 8);
        const float4 a = p[0], b = p[1];
        float s2 = a.x*a.x + a.y*a.y + a.z*a.z + a.w*a.w
                 + b.x*b.x + b.y*b.y + b.z*b.z + b.w*b.w;
        s2 = wave_sum(s2);
        if (lane == 0) {
            const float nrm = sqrtf(s2);
            sInv[lrow] = 1.0f / fmaxf(nrm, 1e-8f);
            if (s == 0) fn[row] = nrm;
        }
    }
    __syncthreads();

    ulonglong2* blk = Ap + (size_t)(bx * KST + s) * SLOTS;
    #pragma unroll
    for (int i = 0; i < 2; ++i) {
        const int v = i * 256 + t;           // slot 0..511
        const int q2 = v >> 6, l = v & 63;
        const int mfr = q2 >> 1, k32 = q2 & 1;
        const int lrow = mfr * 32 + (l & 31);
        const int row = bx * BMt + lrow;
        const int kb = s * BKt + k32 * 32 + ((l >> 5) << 3);
        const float sc = sInv[lrow];
        float xs[8];
        *reinterpret_cast<float4*>(&xs[0]) = *reinterpret_cast<const float4*>(&f[(size_t)row * D + kb]);
        *reinterpret_cast<float4*>(&xs[4]) = *reinterpret_cast<const float4*>(&f[(size_t)row * D + kb + 4]);
        const unsigned long long lo = pack8_fp8(xs, sc);
        *reinterpret_cast<float4*>(&xs[0]) = *reinterpret_cast<const float4*>(&f[(size_t)row * D + kb + 16]);
        *reinterpret_cast<float4*>(&xs[4]) = *reinterpret_cast<const float4*>(&f[(size_t)row * D + kb + 20]);
        const unsigned long long hi = pack8_fp8(xs, sc);
        blk[v] = make_ulonglong2(lo, hi);
    }
}

// Fused norm + pack for W columns -> fp8; zero-fill cols >= C.
// grid (NPAN, KST/2): 2 k-steps per block.
__global__ void pack_b_kernel(const float* __restrict__ wsrc, ulonglong2* __restrict__ Bp,
                              float* __restrict__ wn) {
    __shared__ float sInv[BNt];
    const int pan = blockIdx.x, sg = blockIdx.y;
    const int t = threadIdx.x, lane = t & 63, w = t >> 6;

    for (int rr = 0; rr < 32; ++rr) {
        const int lcol = w * 32 + rr;
        const int col = pan * BNt + lcol;
        float s2 = 0.0f;
        if (col < C) {
            const float4* p = reinterpret_cast<const float4*>(wsrc + (size_t)col * D + lane * 8);
            const float4 a = p[0], b = p[1];
            s2 = a.x*a.x + a.y*a.y + a.z*a.z + a.w*a.w
               + b.x*b.x + b.y*b.y + b.z*b.z + b.w*b.w;
        }
        s2 = wave_sum(s2);
        if (lane == 0) {
            const float nrm = sqrtf(s2);
            sInv[lcol] = (col < C) ? (1.0f / fmaxf(nrm, 1e-8f)) : 0.0f;
            if (sg == 0 && col < C) wn[col] = nrm;
        }
    }
    __syncthreads();

    for (int ss = 0; ss < 2; ++ss) {
        const int s = sg * 2 + ss;
        ulonglong2* blk = Bp + (size_t)(pan * KST + s) * SLOTS;
        #pragma unroll
        for (int i = 0; i < 2; ++i) {
            const int v = i * 256 + t;
            const int q2 = v >> 6, l = v & 63;
            const int mfr = q2 >> 1, k32 = q2 & 1;
            const int lcol = mfr * 32 + (l & 31);
            const int col = pan * BNt + lcol;
            ulonglong2 slot = make_ulonglong2(0ull, 0ull);
            if (col < C) {
                const int kb = s * BKt + k32 * 32 + ((l >> 5) << 3);
                const float sc = sInv[lcol];
                float xs[8];
                *reinterpret_cast<float4*>(&xs[0]) = *reinterpret_cast<const float4*>(&wsrc[(size_t)col * D + kb]);
                *reinterpret_cast<float4*>(&xs[4]) = *reinterpret_cast<const float4*>(&wsrc[(size_t)col * D + kb + 4]);
                slot.x = pack8_fp8(xs, sc);
                *reinterpret_cast<float4*>(&xs[0]) = *reinterpret_cast<const float4*>(&wsrc[(size_t)col * D + kb + 16]);
                *reinterpret_cast<float4*>(&xs[4]) = *reinterpret_cast<const float4*>(&wsrc[(size_t)col * D + kb + 20]);
                slot.y = pack8_fp8(xs, sc);
            }
            blk[v] = slot;
        }
    }
}

// FP8 MFMA GEMM on normalized panels, fragments global->VGPR (no LDS, no
// main-loop barriers). Transposed accumulate: lane&31 owns one logit ROW.
// Fragment bytes and load count HALVED vs f16 (one 16B slot = 2 k16 frags).
// pZ[row][panel] = sum_cols exp(30*cos - 30).
__global__ __launch_bounds__(256, 4) void
gemm_mfma_kernel(const ulonglong2* __restrict__ Ap, const ulonglong2* __restrict__ Bp,
                 float* __restrict__ pZ)
{
    __shared__ float sRed[BMt][2];
    const int wgid = blockIdx.x;
    const int swz = (wgid & 7) * (NWG / 8) + (wgid >> 3);   // bijective (NWG%8==0)
    const int bx = swz & 15;          // row tile
    const int by = swz >> 4;          // panel
    const int tid  = threadIdx.x;
    const int lane = tid & 63;
    const int half = lane >> 5, l31 = lane & 31;
    const int w    = tid >> 6;
    const int wm   = w >> 1;          // 0..1
    const int wnn  = w & 1;           // 0..1

    const ulonglong2* Aw = Ap + (size_t)bx * KST * SLOTS + (wm * 4) * 64 + lane;
    const ulonglong2* Bw = Bp + (size_t)by * KST * SLOTS + (wnn * 4) * 64 + lane;

    f32x16 accT00, accT01, accT10, accT11;   // cols(lane&31)=logit rows
    #pragma unroll
    for (int i = 0; i < 16; ++i) { accT00[i] = 0.f; accT01[i] = 0.f; accT10[i] = 0.f; accT11[i] = 0.f; }

    #pragma unroll 2
    for (int s = 0; s < KST; ++s) {
        const ulonglong2* As = Aw + s * SLOTS;
        const ulonglong2* Bs = Bw + s * SLOTS;
        // 8 dwordx4 loads cover the whole k-step (4 k16 x {a0,a1,b0,b1})
        const ulonglong2 a0k0 = As[0 * 64];        // i=0,k32=0
        const ulonglong2 a0k1 = As[1 * 64];        // i=0,k32=1
        const ulonglong2 a1k0 = As[2 * 64];        // i=1,k32=0
        const ulonglong2 a1k1 = As[3 * 64];        // i=1,k32=1
        const ulonglong2 b0k0 = Bs[0 * 64];
        const ulonglong2 b0k1 = Bs[1 * 64];
        const ulonglong2 b1k0 = Bs[2 * 64];
        const ulonglong2 b1k1 = Bs[3 * 64];
        #pragma unroll
        for (int k16 = 0; k16 < 4; ++k16) {
            const int k32 = k16 >> 1, h = k16 & 1;
            const long af0 = (long)(h ? (k32 ? a0k1.y : a0k0.y) : (k32 ? a0k1.x : a0k0.x));
            const long af1 = (long)(h ? (k32 ? a1k1.y : a1k0.y) : (k32 ? a1k1.x : a1k0.x));
            const long bf0 = (long)(h ? (k32 ? b0k1.y : b0k0.y) : (k32 ? b0k1.x : b0k0.x));
            const long bf1 = (long)(h ? (k32 ? b1k1.y : b1k0.y) : (k32 ? b1k1.x : b1k0.x));
            mfma_fp8_t(accT00, bf0, af0);  // rows wm*64+l31,    cols wnn*64 + r-map
            mfma_fp8_t(accT01, bf0, af1);  // rows wm*64+32+l31
            mfma_fp8_t(accT10, bf1, af0);  // cols +32
            mfma_fp8_t(accT11, bf1, af1);
        }
    }

    // ---- epilogue: per-lane row partials, single cross-lane step ----
    float zA = 0.0f;   // row = wm*64 + l31
    float zB = 0.0f;   // row = wm*64 + 32 + l31
    const int cbase = by * BNt + wnn * 64 + 4 * half;
    #pragma unroll
    for (int r = 0; r < 16; ++r) {
        const int cb = cbase + (r & 3) + 8 * (r >> 2);
        const float eA0 = (cb      < C) ? __expf(fmaf(accT00[r], S_SCALE, -MFIX)) : 0.0f;
        const float eB0 = (cb      < C) ? __expf(fmaf(accT01[r], S_SCALE, -MFIX)) : 0.0f;
        const float eA1 = (cb + 32 < C) ? __expf(fmaf(accT10[r], S_SCALE, -MFIX)) : 0.0f;
        const float eB1 = (cb + 32 < C) ? __expf(fmaf(accT11[r], S_SCALE, -MFIX)) : 0.0f;
        zA += eA0 + eA1;
        zB += eB0 + eB1;
    }
    zA += __shfl_xor(zA, 32, 64);    // combine the two col-halves of each row
    zB += __shfl_xor(zB, 32, 64);
    if (half == 0) {
        sRed[wm * 64 + l31][wnn]      = zA;
        sRed[wm * 64 + 32 + l31][wnn] = zB;
    }
    __syncthreads();
    if (tid < BMt) {
        pZ[(size_t)(bx * BMt + tid) * NPAN + by] = sRed[tid][0] + sRed[tid][1];
    }
}

// One wave per row: sum NPAN partials (fixed shift M=30), exact fp32 target
// logits + ArcFace margin, correct Z, emit per-row loss.
__global__ void finalize_kernel(const float* __restrict__ f, const float* __restrict__ w,
                                const float* __restrict__ fn, const float* __restrict__ wn,
                                const int* __restrict__ pinds, const int* __restrict__ lengths,
                                const float* __restrict__ pZ, float* __restrict__ loss)
{
    const int b = blockIdx.x;
    const int lane = threadIdx.x;

    float Zp = 0.0f;
    for (int p = lane; p < NPAN; p += 64) Zp += pZ[(size_t)b * NPAN + p];
    Zp = wave_sum(Zp);

    const float4* fp = reinterpret_cast<const float4*>(f + (size_t)b * D);
    const float4 a0 = fp[lane * 2 + 0];
    const float4 a1 = fp[lane * 2 + 1];
    const float fnb = fn[b];
    const int len = lengths[b];

    float opl[LMAX], ops[LMAX];
    int cs[LMAX];
    #pragma unroll
    for (int j = 0; j < LMAX; ++j) {
        const int c = pinds[(size_t)b * LMAX + j];
        cs[j] = c;
        const float4* wp = reinterpret_cast<const float4*>(w + (size_t)c * D);
        const float4 w0 = wp[lane * 2 + 0];
        const float4 w1 = wp[lane * 2 + 1];
        float d = a0.x*w0.x + a0.y*w0.y + a0.z*w0.z + a0.w*w0.w
                + a1.x*w1.x + a1.y*w1.y + a1.z*w1.z + a1.w*w1.w;
        d = wave_sum(d);
        const float cosv = d / fmaxf(fnb * wn[c], 1e-8f);
        const float sine = sqrtf(fminf(fmaxf(1.0f - cosv * cosv, 0.0f), 1.0f));
        float phi = cosv * COS_M - sine * SIN_M;
        phi = (cosv > TH) ? phi : (cosv - MM);
        opl[j] = S_SCALE * cosv;
        ops[j] = S_SCALE * phi;
    }

    // correct Z for unique positive classes (margin applied), then ragged CE
    float Zc = Zp;
    for (int j = 0; j < len; ++j) {
        bool dup = false;
        for (int jj = 0; jj < j; ++jj) dup = dup || (cs[jj] == cs[j]);
        if (!dup) Zc += expf(ops[j] - MFIX) - expf(opl[j] - MFIX);
    }
    const float lZ = logf(Zc);
    float acc = 0.0f;
    for (int j = 0; j < len; ++j) acc += (MFIX + lZ - ops[j]);
    const float Lf = (float)len;
    if (lane == 0) loss[b] = acc / (Lf * Lf);
}

__global__ void reduce_kernel(const float* __restrict__ loss, float* __restrict__ out) {
    __shared__ float sdata[256];
    const int t = threadIdx.x;
    float s = 0.0f;
    for (int i = t; i < B; i += 256) s += loss[i];
    sdata[t] = s;
    __syncthreads();
    for (int off = 128; off > 0; off >>= 1) {
        if (t < off) sdata[t] += sdata[t + off];
        __syncthreads();
    }
    if (t == 0) out[0] = sdata[0] * (1.0f / (float)B);
}

} // anonymous namespace

extern "C" void kernel_launch(void* const* d_in, const int* in_sizes, int n_in,
                              void* d_out, int out_size, void* d_ws, size_t ws_size,
                              hipStream_t stream) {
    const float* f   = (const float*)d_in[0];
    // d_in[1] = labels [B,C] — not needed (reconstructed from pinds/lengths)
    const float* w   = (const float*)d_in[2];
    const int* pinds = (const int*)d_in[3];
    const int* lens  = (const int*)d_in[4];
    float* out = (float*)d_out;

    char* ws = (char*)d_ws;
    size_t off = 0;
    auto alloc = [&](size_t bytes) { void* p = ws + off; off = (off + bytes + 255) & ~(size_t)255; return p; };

    float* wn   = (float*)alloc(C * 4);
    float* fn   = (float*)alloc(B * 4);
    float* pZ   = (float*)alloc((size_t)B * NPAN * 4);
    float* loss = (float*)alloc(B * 4);
    ulonglong2* Ap = (ulonglong2*)alloc((size_t)NROWT * KST * SLOTS * 16);
    ulonglong2* Bp = (ulonglong2*)alloc((size_t)NPAN  * KST * SLOTS * 16);

    pack_a_kernel<<<dim3(NROWT, KST), 256, 0, stream>>>(f, Ap, fn);
    pack_b_kernel<<<dim3(NPAN, KST / 2), 256, 0, stream>>>(w, Bp, wn);
    gemm_mfma_kernel<<<dim3(NWG), 256, 0, stream>>>(Ap, Bp, pZ);
    finalize_kernel<<<dim3(B), 64, 0, stream>>>(f, w, fn, wn, pinds, lens, pZ, loss);
    reduce_kernel<<<dim3(1), 256, 0, stream>>>(loss, out);
}

// Round 12
// 82.214 us; speedup vs baseline: 1.7038x; 1.3244x over previous
//
#include <hip/hip_runtime.h>
#include <math.h>

namespace {

constexpr int B = 2048;
constexpr int C = 20000;
constexpr int D = 512;
constexpr int LMAX = 8;

constexpr int BMt = 128, BNt = 128, BKt = 64;
constexpr int NROWT = B / BMt;               // 16 row tiles
constexpr int NPAN  = (C + BNt - 1) / BNt;   // 157 col panels (last has 32 valid)
constexpr int KST   = D / BKt;               // 8 K-steps
constexpr int SLOTS = 512;                   // 16B slots per (tile,kstep): q2=m_frag*2+k32
constexpr int NWG   = NROWT * NPAN;          // 2512 (divisible by 8 XCDs)

constexpr float S_SCALE = 30.0f;
constexpr float COS_M = 0.87758256189037271f;   // cos(0.5)
constexpr float SIN_M = 0.47942553860420301f;   // sin(0.5)
constexpr float TH    = -0.87758256189037271f;  // cos(pi - 0.5)
constexpr float MM    = 0.23971276930210156f;   // sin(pi - 0.5) * 0.5
constexpr float MFIX  = 30.0f;                  // fixed softmax shift: |logits| <= 30

typedef float f32x16 __attribute__((ext_vector_type(16)));

__device__ __forceinline__ void mfma_fp8_t(f32x16& acc, long bfrag, long afrag) {
    // transposed: builtin(A=bfrag, B=afrag) -> D cols (lane&31) = logit ROWS
    acc = __builtin_amdgcn_mfma_f32_32x32x16_fp8_fp8(bfrag, afrag, acc, 0, 0, 0);
}

// 8 fp32 -> 8 fp8 e4m3 bytes (hardware RNE pack), element j = byte j
__device__ __forceinline__ unsigned long long pack8_fp8(const float* xs, float sc) {
    int d0 = __builtin_amdgcn_cvt_pk_fp8_f32(xs[0] * sc, xs[1] * sc, 0, false);
    d0 = __builtin_amdgcn_cvt_pk_fp8_f32(xs[2] * sc, xs[3] * sc, d0, true);
    int d1 = __builtin_amdgcn_cvt_pk_fp8_f32(xs[4] * sc, xs[5] * sc, 0, false);
    d1 = __builtin_amdgcn_cvt_pk_fp8_f32(xs[6] * sc, xs[7] * sc, d1, true);
    return (unsigned long long)(unsigned)d0 | ((unsigned long long)(unsigned)d1 << 32);
}

__device__ __forceinline__ float wave_sum(float v) {
    #pragma unroll
    for (int off = 1; off < 64; off <<= 1) v += __shfl_xor(v, off, 64);
    return v;
}

// one wave per row: norm + inverse norm over D=512 (reads data exactly once)
__global__ void norm_kernel(const float* __restrict__ x, float* __restrict__ nrm_out,
                            float* __restrict__ inv_out, int rows) {
    const int wave = threadIdx.x >> 6, lane = threadIdx.x & 63;
    const int row = blockIdx.x * 4 + wave;
    if (row >= rows) return;
    const float4* p = reinterpret_cast<const float4*>(x + (size_t)row * D);
    const float4 a = p[lane * 2 + 0];
    const float4 b = p[lane * 2 + 1];
    float s = a.x*a.x + a.y*a.y + a.z*a.z + a.w*a.w
            + b.x*b.x + b.y*b.y + b.z*b.z + b.w*b.w;
    s = wave_sum(s);
    if (lane == 0) {
        const float nrm = sqrtf(s);
        nrm_out[row] = nrm;
        inv_out[row] = 1.0f / fmaxf(nrm, 1e-8f);
    }
}

// Pack f -> fp8 e4m3 panels, pre-normalized (GEMM emits cosine directly).
// grid (NROWT, KST): reads each element exactly once; inv norms from global.
// Slot u = q2*64 + l, q2 = m_frag*2 + k32. Slot.x/.y = k16 pair:
//   half h elems j: row = m_frag*32 + (l&31), k = k32*32 + h*16 + (l>>5)*8 + j.
__global__ void pack_a_kernel(const float* __restrict__ f, const float* __restrict__ finv,
                              ulonglong2* __restrict__ Ap) {
    const int bx = blockIdx.x, s = blockIdx.y;
    const int t = threadIdx.x;
    ulonglong2* blk = Ap + (size_t)(bx * KST + s) * SLOTS;
    #pragma unroll
    for (int i = 0; i < 2; ++i) {
        const int v = i * 256 + t;           // slot 0..511
        const int q2 = v >> 6, l = v & 63;
        const int mfr = q2 >> 1, k32 = q2 & 1;
        const int lrow = mfr * 32 + (l & 31);
        const int row = bx * BMt + lrow;
        const int kb = s * BKt + k32 * 32 + ((l >> 5) << 3);
        const float sc = finv[row];
        float xs[8];
        *reinterpret_cast<float4*>(&xs[0]) = *reinterpret_cast<const float4*>(&f[(size_t)row * D + kb]);
        *reinterpret_cast<float4*>(&xs[4]) = *reinterpret_cast<const float4*>(&f[(size_t)row * D + kb + 4]);
        const unsigned long long lo = pack8_fp8(xs, sc);
        *reinterpret_cast<float4*>(&xs[0]) = *reinterpret_cast<const float4*>(&f[(size_t)row * D + kb + 16]);
        *reinterpret_cast<float4*>(&xs[4]) = *reinterpret_cast<const float4*>(&f[(size_t)row * D + kb + 20]);
        const unsigned long long hi = pack8_fp8(xs, sc);
        blk[v] = make_ulonglong2(lo, hi);
    }
}

// Pack W columns -> fp8; zero-fill cols >= C. grid (NPAN, KST), single-touch reads.
__global__ void pack_b_kernel(const float* __restrict__ wsrc, const float* __restrict__ winv,
                              ulonglong2* __restrict__ Bp) {
    const int pan = blockIdx.x, s = blockIdx.y;
    const int t = threadIdx.x;
    ulonglong2* blk = Bp + (size_t)(pan * KST + s) * SLOTS;
    #pragma unroll
    for (int i = 0; i < 2; ++i) {
        const int v = i * 256 + t;
        const int q2 = v >> 6, l = v & 63;
        const int mfr = q2 >> 1, k32 = q2 & 1;
        const int lcol = mfr * 32 + (l & 31);
        const int col = pan * BNt + lcol;
        ulonglong2 slot = make_ulonglong2(0ull, 0ull);
        if (col < C) {
            const int kb = s * BKt + k32 * 32 + ((l >> 5) << 3);
            const float sc = winv[col];
            float xs[8];
            *reinterpret_cast<float4*>(&xs[0]) = *reinterpret_cast<const float4*>(&wsrc[(size_t)col * D + kb]);
            *reinterpret_cast<float4*>(&xs[4]) = *reinterpret_cast<const float4*>(&wsrc[(size_t)col * D + kb + 4]);
            slot.x = pack8_fp8(xs, sc);
            *reinterpret_cast<float4*>(&xs[0]) = *reinterpret_cast<const float4*>(&wsrc[(size_t)col * D + kb + 16]);
            *reinterpret_cast<float4*>(&xs[4]) = *reinterpret_cast<const float4*>(&wsrc[(size_t)col * D + kb + 20]);
            slot.y = pack8_fp8(xs, sc);
        }
        blk[v] = slot;
    }
}

// FP8 MFMA GEMM on normalized panels, fragments global->VGPR with an explicit
// 2-deep software pipeline (issue step s+1's loads BEFORE step s's MFMAs).
// No LDS staging, no main-loop barriers. Transposed accumulate: lane&31 owns
// one logit ROW. pZ[row][panel] = sum_cols exp(30*cos - 30).
// launch_bounds(256,3): VGPR cap ~170 so cur+next fragment sets both fit.
__global__ __launch_bounds__(256, 3) void
gemm_mfma_kernel(const ulonglong2* __restrict__ Ap, const ulonglong2* __restrict__ Bp,
                 float* __restrict__ pZ)
{
    __shared__ float sRed[BMt][2];
    const int wgid = blockIdx.x;
    const int swz = (wgid & 7) * (NWG / 8) + (wgid >> 3);   // bijective (NWG%8==0)
    const int bx = swz & 15;          // row tile
    const int by = swz >> 4;          // panel
    const int tid  = threadIdx.x;
    const int lane = tid & 63;
    const int half = lane >> 5, l31 = lane & 31;
    const int w    = tid >> 6;
    const int wm   = w >> 1;          // 0..1
    const int wnn  = w & 1;           // 0..1

    const ulonglong2* Aw = Ap + (size_t)bx * KST * SLOTS + (wm * 4) * 64 + lane;
    const ulonglong2* Bw = Bp + (size_t)by * KST * SLOTS + (wnn * 4) * 64 + lane;

    f32x16 accT00, accT01, accT10, accT11;   // cols(lane&31)=logit rows
    #pragma unroll
    for (int i = 0; i < 16; ++i) { accT00[i] = 0.f; accT01[i] = 0.f; accT10[i] = 0.f; accT11[i] = 0.f; }

    // prologue: load step 0
    ulonglong2 ca0 = Aw[0],   ca1 = Aw[64],  ca2 = Aw[128], ca3 = Aw[192];
    ulonglong2 cb0 = Bw[0],   cb1 = Bw[64],  cb2 = Bw[128], cb3 = Bw[192];

    #pragma unroll
    for (int s = 0; s < KST; ++s) {
        ulonglong2 na0, na1, na2, na3, nb0, nb1, nb2, nb3;
        if (s + 1 < KST) {                       // issue next-step loads FIRST
            const ulonglong2* As = Aw + (s + 1) * SLOTS;
            const ulonglong2* Bs = Bw + (s + 1) * SLOTS;
            na0 = As[0]; na1 = As[64]; na2 = As[128]; na3 = As[192];
            nb0 = Bs[0]; nb1 = Bs[64]; nb2 = Bs[128]; nb3 = Bs[192];
        }
        // 16 MFMAs on current fragments (k16 = {k32,h}: slot pair .x/.y)
        mfma_fp8_t(accT00, (long)cb0.x, (long)ca0.x);
        mfma_fp8_t(accT01, (long)cb0.x, (long)ca2.x);
        mfma_fp8_t(accT10, (long)cb2.x, (long)ca0.x);
        mfma_fp8_t(accT11, (long)cb2.x, (long)ca2.x);
        mfma_fp8_t(accT00, (long)cb0.y, (long)ca0.y);
        mfma_fp8_t(accT01, (long)cb0.y, (long)ca2.y);
        mfma_fp8_t(accT10, (long)cb2.y, (long)ca0.y);
        mfma_fp8_t(accT11, (long)cb2.y, (long)ca2.y);
        mfma_fp8_t(accT00, (long)cb1.x, (long)ca1.x);
        mfma_fp8_t(accT01, (long)cb1.x, (long)ca3.x);
        mfma_fp8_t(accT10, (long)cb3.x, (long)ca1.x);
        mfma_fp8_t(accT11, (long)cb3.x, (long)ca3.x);
        mfma_fp8_t(accT00, (long)cb1.y, (long)ca1.y);
        mfma_fp8_t(accT01, (long)cb1.y, (long)ca3.y);
        mfma_fp8_t(accT10, (long)cb3.y, (long)ca1.y);
        mfma_fp8_t(accT11, (long)cb3.y, (long)ca3.y);
        if (s + 1 < KST) {
            ca0 = na0; ca1 = na1; ca2 = na2; ca3 = na3;
            cb0 = nb0; cb1 = nb1; cb2 = nb2; cb3 = nb3;
        }
    }

    // ---- epilogue: per-lane row partials, single cross-lane step ----
    float zA = 0.0f;   // row = wm*64 + l31
    float zB = 0.0f;   // row = wm*64 + 32 + l31
    const int cbase = by * BNt + wnn * 64 + 4 * half;
    #pragma unroll
    for (int r = 0; r < 16; ++r) {
        const int cb = cbase + (r & 3) + 8 * (r >> 2);
        const float eA0 = (cb      < C) ? __expf(fmaf(accT00[r], S_SCALE, -MFIX)) : 0.0f;
        const float eB0 = (cb      < C) ? __expf(fmaf(accT01[r], S_SCALE, -MFIX)) : 0.0f;
        const float eA1 = (cb + 32 < C) ? __expf(fmaf(accT10[r], S_SCALE, -MFIX)) : 0.0f;
        const float eB1 = (cb + 32 < C) ? __expf(fmaf(accT11[r], S_SCALE, -MFIX)) : 0.0f;
        zA += eA0 + eA1;
        zB += eB0 + eB1;
    }
    zA += __shfl_xor(zA, 32, 64);    // combine the two col-halves of each row
    zB += __shfl_xor(zB, 32, 64);
    if (half == 0) {
        sRed[wm * 64 + l31][wnn]      = zA;
        sRed[wm * 64 + 32 + l31][wnn] = zB;
    }
    __syncthreads();
    if (tid < BMt) {
        pZ[(size_t)(bx * BMt + tid) * NPAN + by] = sRed[tid][0] + sRed[tid][1];
    }
}

// One wave per row: sum NPAN partials (fixed shift M=30), exact fp32 target
// logits + ArcFace margin, correct Z, emit per-row loss.
__global__ void finalize_kernel(const float* __restrict__ f, const float* __restrict__ w,
                                const float* __restrict__ fn, const float* __restrict__ wn,
                                const int* __restrict__ pinds, const int* __restrict__ lengths,
                                const float* __restrict__ pZ, float* __restrict__ loss)
{
    const int b = blockIdx.x;
    const int lane = threadIdx.x;

    float Zp = 0.0f;
    for (int p = lane; p < NPAN; p += 64) Zp += pZ[(size_t)b * NPAN + p];
    Zp = wave_sum(Zp);

    const float4* fp = reinterpret_cast<const float4*>(f + (size_t)b * D);
    const float4 a0 = fp[lane * 2 + 0];
    const float4 a1 = fp[lane * 2 + 1];
    const float fnb = fn[b];
    const int len = lengths[b];

    float opl[LMAX], ops[LMAX];
    int cs[LMAX];
    #pragma unroll
    for (int j = 0; j < LMAX; ++j) {
        const int c = pinds[(size_t)b * LMAX + j];
        cs[j] = c;
        const float4* wp = reinterpret_cast<const float4*>(w + (size_t)c * D);
        const float4 w0 = wp[lane * 2 + 0];
        const float4 w1 = wp[lane * 2 + 1];
        float d = a0.x*w0.x + a0.y*w0.y + a0.z*w0.z + a0.w*w0.w
                + a1.x*w1.x + a1.y*w1.y + a1.z*w1.z + a1.w*w1.w;
        d = wave_sum(d);
        const float cosv = d / fmaxf(fnb * wn[c], 1e-8f);
        const float sine = sqrtf(fminf(fmaxf(1.0f - cosv * cosv, 0.0f), 1.0f));
        float phi = cosv * COS_M - sine * SIN_M;
        phi = (cosv > TH) ? phi : (cosv - MM);
        opl[j] = S_SCALE * cosv;
        ops[j] = S_SCALE * phi;
    }

    // correct Z for unique positive classes (margin applied), then ragged CE
    float Zc = Zp;
    for (int j = 0; j < len; ++j) {
        bool dup = false;
        for (int jj = 0; jj < j; ++jj) dup = dup || (cs[jj] == cs[j]);
        if (!dup) Zc += expf(ops[j] - MFIX) - expf(opl[j] - MFIX);
    }
    const float lZ = logf(Zc);
    float acc = 0.0f;
    for (int j = 0; j < len; ++j) acc += (MFIX + lZ - ops[j]);
    const float Lf = (float)len;
    if (lane == 0) loss[b] = acc / (Lf * Lf);
}

__global__ void reduce_kernel(const float* __restrict__ loss, float* __restrict__ out) {
    __shared__ float sdata[256];
    const int t = threadIdx.x;
    float s = 0.0f;
    for (int i = t; i < B; i += 256) s += loss[i];
    sdata[t] = s;
    __syncthreads();
    for (int off = 128; off > 0; off >>= 1) {
        if (t < off) sdata[t] += sdata[t + off];
        __syncthreads();
    }
    if (t == 0) out[0] = sdata[0] * (1.0f / (float)B);
}

} // anonymous namespace

extern "C" void kernel_launch(void* const* d_in, const int* in_sizes, int n_in,
                              void* d_out, int out_size, void* d_ws, size_t ws_size,
                              hipStream_t stream) {
    const float* f   = (const float*)d_in[0];
    // d_in[1] = labels [B,C] — not needed (reconstructed from pinds/lengths)
    const float* w   = (const float*)d_in[2];
    const int* pinds = (const int*)d_in[3];
    const int* lens  = (const int*)d_in[4];
    float* out = (float*)d_out;

    char* ws = (char*)d_ws;
    size_t off = 0;
    auto alloc = [&](size_t bytes) { void* p = ws + off; off = (off + bytes + 255) & ~(size_t)255; return p; };

    float* wn   = (float*)alloc(C * 4);
    float* winv = (float*)alloc(C * 4);
    float* fn   = (float*)alloc(B * 4);
    float* finv = (float*)alloc(B * 4);
    float* pZ   = (float*)alloc((size_t)B * NPAN * 4);
    float* loss = (float*)alloc(B * 4);
    ulonglong2* Ap = (ulonglong2*)alloc((size_t)NROWT * KST * SLOTS * 16);
    ulonglong2* Bp = (ulonglong2*)alloc((size_t)NPAN  * KST * SLOTS * 16);

    norm_kernel<<<dim3(B / 4), 256, 0, stream>>>(f, fn, finv, B);
    norm_kernel<<<dim3(C / 4), 256, 0, stream>>>(w, wn, winv, C);
    pack_a_kernel<<<dim3(NROWT, KST), 256, 0, stream>>>(f, finv, Ap);
    pack_b_kernel<<<dim3(NPAN, KST), 256, 0, stream>>>(w, winv, Bp);
    gemm_mfma_kernel<<<dim3(NWG), 256, 0, stream>>>(Ap, Bp, pZ);
    finalize_kernel<<<dim3(B), 64, 0, stream>>>(f, w, fn, wn, pinds, lens, pZ, loss);
    reduce_kernel<<<dim3(1), 256, 0, stream>>>(loss, out);
}